// Round 9
// baseline (442.761 us; speedup 1.0000x reference)
//
#include <hip/hip_runtime.h>

#define N_SP 16384
#define C_DIM 128
#define K_DIM 32
#define B_DIM 32

typedef short short8 __attribute__((ext_vector_type(8)));
typedef float f32x16 __attribute__((ext_vector_type(16)));

__device__ __forceinline__ unsigned f2bfu(float f){
    return (__float_as_uint(f) + 0x8000u) >> 16;   // cheap RN to bf16 bits
}
__device__ __forceinline__ unsigned short f2bf(float f){
    return (unsigned short)f2bfu(f);
}

union FragU { int i[4]; short8 s; };

// ============================ PASS 1: transpose =============================
// tile [32 c][1024 n] bf16, 8B-granular swizzle (write uint2, read u16)
#define SWT(c, n) (((c) << 10) + ((n) ^ (((c) & 15) << 2)))

__global__ __launch_bounds__(256, 2) void enc_transpose(
    const float* __restrict__ x,            // [B][C][N]
    unsigned short* __restrict__ xt,        // [B][N][C] bf16 out
    float* __restrict__ x2p)                // [4 cc][B][N] fp32 partial ||x||^2
{
    __shared__ __align__(16) unsigned short tile[32 * 1024];  // 64 KB
    __shared__ float x2l[1024];                               // 4 KB

    const int t  = threadIdx.x;      // 0..255
    const int w  = t >> 6;           // wave 0..3 -> rows 8w..8w+7
    const int l  = t & 63;
    const int n0 = blockIdx.x * 1024;
    const int b  = blockIdx.y;
    const int cc = blockIdx.z;
    const int c0 = cc * 32;

#pragma unroll
    for (int it = 0; it < 4; ++it) x2l[it * 256 + t] = 0.f;
    __syncthreads();

    // wave w streams rows c0+8w .. c0+8w+7; per row 4 consecutive 1KB instrs
    const float* basep = x + (size_t)b * (C_DIM * N_SP)
                           + (size_t)(c0 + 8 * w) * N_SP + n0;
    float p2[4][4];
#pragma unroll
    for (int ch = 0; ch < 4; ++ch)
#pragma unroll
        for (int j = 0; j < 4; ++j) p2[ch][j] = 0.f;

    float4 cur[4], nxt[4];
#pragma unroll
    for (int ch = 0; ch < 4; ++ch)
        cur[ch] = *(const float4*)(basep + ch * 256 + 4 * l);

#pragma unroll
    for (int r = 0; r < 8; ++r){
        if (r < 7){
#pragma unroll
            for (int ch = 0; ch < 4; ++ch)
                nxt[ch] = *(const float4*)(basep + (size_t)(r + 1) * N_SP + ch * 256 + 4 * l);
        }
        const int cl = 8 * w + r;    // local c row (0..31)
#pragma unroll
        for (int ch = 0; ch < 4; ++ch){
            const float4 v = cur[ch];
            p2[ch][0] = fmaf(v.x, v.x, p2[ch][0]);
            p2[ch][1] = fmaf(v.y, v.y, p2[ch][1]);
            p2[ch][2] = fmaf(v.z, v.z, p2[ch][2]);
            p2[ch][3] = fmaf(v.w, v.w, p2[ch][3]);
            uint2 uu;
            uu.x = f2bfu(v.x) | (f2bfu(v.y) << 16);
            uu.y = f2bfu(v.z) | (f2bfu(v.w) << 16);
            *(uint2*)&tile[SWT(cl, ch * 256 + 4 * l)] = uu;
        }
#pragma unroll
        for (int ch = 0; ch < 4; ++ch) cur[ch] = nxt[ch];
    }
    // exact fp32 x2 partials: per-thread 8-row presum, one LDS add per column
#pragma unroll
    for (int ch = 0; ch < 4; ++ch)
#pragma unroll
        for (int j = 0; j < 4; ++j)
            atomicAdd(&x2l[ch * 256 + 4 * l + j], p2[ch][j]);

    __syncthreads();

    // output: thread t owns n = it*256+t; gather 32 c, store 64B line
    unsigned short* xtb = xt + ((size_t)(b * N_SP + n0)) * C_DIM + c0;
    float* x2o = x2p + (size_t)cc * (B_DIM * N_SP) + (size_t)b * N_SP + n0;
#pragma unroll
    for (int it = 0; it < 4; ++it){
        const int n = it * 256 + t;
        unsigned q[16];
#pragma unroll
        for (int i = 0; i < 16; ++i){
            const unsigned lo  = tile[SWT(2 * i,     n)];
            const unsigned h16 = tile[SWT(2 * i + 1, n)];
            q[i] = lo | (h16 << 16);
        }
        uint4* dst = (uint4*)(xtb + (size_t)n * C_DIM);
        uint4 u0; u0.x = q[0];  u0.y = q[1];  u0.z = q[2];  u0.w = q[3];
        uint4 u1; u1.x = q[4];  u1.y = q[5];  u1.z = q[6];  u1.w = q[7];
        uint4 u2; u2.x = q[8];  u2.y = q[9];  u2.z = q[10]; u2.w = q[11];
        uint4 u3; u3.x = q[12]; u3.y = q[13]; u3.z = q[14]; u3.w = q[15];
        dst[0] = u0; dst[1] = u1; dst[2] = u2; dst[3] = u3;
        x2o[n] = x2l[n];
    }
}

// ============================ PASS 2: encoding ==============================
// xs: [128 n][128 c] bf16, 16B-granular swizzle; aws: [32 k][128 n]
#define SX(n, c)  (((n) << 7) + ((c) ^ (((n) & 15) << 3)))
#define SWA(k, n) (((k) << 7) + ((n) ^ (((k) & 15) << 3)))

__global__ __launch_bounds__(256, 3) void enc_main2(
    const unsigned short* __restrict__ xt,     // [B][N][C] bf16
    const float* __restrict__ x2p,             // [4][B][N]
    const unsigned short* __restrict__ cwt2b,  // [K][C] bf16 of -2*scale*cw
    const float* __restrict__ combo,           // [K][2] = {scale, scale*||cw||^2}
    float* __restrict__ wxacc,                 // [B][K][C] (zeroed)
    float* __restrict__ wsacc)                 // [B][K]    (zeroed)
{
    __shared__ __align__(16) unsigned short xs[128 * C_DIM];   // 32 KB
    __shared__ __align__(16) unsigned short aws[K_DIM * 128];  // 8 KB
    __shared__ float x2s[128];

    const int t   = threadIdx.x;    // 0..255
    const int w   = t >> 6;         // wave 0..3
    const int hi  = (t >> 5) & 1;
    const int l31 = t & 31;
    const int n0  = blockIdx.x * 128;
    const int b   = blockIdx.y;

    // held codeword A-frags (proven R5-R8 convention)
    short8 cwA[8];
#pragma unroll
    for (int ksg = 0; ksg < 8; ++ksg)
        cwA[ksg] = *(const short8*)(const void*)(cwt2b + l31 * C_DIM + ksg * 16 + hi * 8);

    short8 ones;
#pragma unroll
    for (int i = 0; i < 8; ++i) ones[i] = (short)0x3F80;  // bf16 1.0

    // ---- load tile: 32KB fully contiguous ----
    const unsigned short* src = xt + ((size_t)(b * N_SP + n0)) * C_DIM;
#pragma unroll
    for (int i = 0; i < 8; ++i){
        const int idx16 = t + i * 256;            // 16B units
        const int n  = idx16 >> 4;
        const int cp = (idx16 & 15) << 3;
        *(uint4*)&xs[SX(n, cp)] = *(const uint4*)(src + (size_t)idx16 * 8);
    }
    if (t < 128){
        const float* xp2 = x2p + (size_t)b * N_SP + n0 + t;
        x2s[t] = xp2[0] + xp2[(size_t)B_DIM * N_SP]
               + xp2[(size_t)2 * B_DIM * N_SP] + xp2[(size_t)3 * B_DIM * N_SP];
    }
    __syncthreads();

    // ---- S phase: S[k][n] = sum_c cw2[k][c] * x[n][c]; wave w owns n-group w ----
    const int ncol = 32 * w + l31;
    f32x16 sA;
#pragma unroll
    for (int i = 0; i < 16; ++i) sA[i] = 0.f;
#pragma unroll
    for (int ks = 0; ks < 8; ++ks){   // c-contract: 8 steps of 16
        short8 bf = *(const short8*)(const void*)&xs[SX(ncol, ks * 16 + hi * 8)];
        sA = __builtin_amdgcn_mfma_f32_32x32x16_bf16(cwA[ks], bf, sA, 0, 0, 0);
    }

    // ---- softmax over k on the MFMA D-layout ----
    float csx[16], csy[16];
#pragma unroll
    for (int q = 0; q < 16; ++q){
        const int row = (q & 3) + 8 * (q >> 2) + 4 * hi;
        csx[q] = combo[2 * row];
        csy[q] = combo[2 * row + 1];
    }
    const float x2g = x2s[ncol];
    {
        float arg[16]; float ml = -3.4e38f;
#pragma unroll
        for (int q = 0; q < 16; ++q){
            arg[q] = fmaf(csx[q], x2g, sA[q] + csy[q]);   // scale*(x2-2x.cw+c2)
            ml = fmaxf(ml, arg[q]);
        }
        const float mm = fmaxf(ml, __shfl_xor(ml, 32));
        float sum = 0.f;
#pragma unroll
        for (int q = 0; q < 16; ++q){ float p = __expf(arg[q] - mm); arg[q] = p; sum += p; }
        sum += __shfl_xor(sum, 32);
        const float r = 1.f / sum;
#pragma unroll
        for (int q = 0; q < 16; ++q){
            const int row = (q & 3) + 8 * (q >> 2) + 4 * hi;
            aws[SWA(row, ncol)] = f2bf(arg[q] * r);
        }
    }
    __syncthreads();

    // ---- D phase: wx[k][c] += aw[k][n] * x[n][c]; wave w owns c-group w ----
    const int cmy = 32 * w + l31;
    f32x16 acc, accS;
#pragma unroll
    for (int i = 0; i < 16; ++i){ acc[i] = 0.f; accS[i] = 0.f; }

#pragma unroll
    for (int ks = 0; ks < 8; ++ks){   // n-contract: 8 steps of 16
        const int nb = ks * 16 + hi * 8;
        short8 af = *(const short8*)(const void*)&aws[SWA(l31, nb)];
        FragU f;
#pragma unroll
        for (int d = 0; d < 4; ++d){
            const unsigned lo  = xs[SX(nb + 2 * d,     cmy)];
            const unsigned h16 = xs[SX(nb + 2 * d + 1, cmy)];
            f.i[d] = (int)(lo | (h16 << 16));
        }
        acc = __builtin_amdgcn_mfma_f32_32x32x16_bf16(af, f.s, acc, 0, 0, 0);
        if ((ks >> 1) == w)
            accS = __builtin_amdgcn_mfma_f32_32x32x16_bf16(af, ones, accS, 0, 0, 0);
    }

    // ---- epilogue: atomic-reduce to global ----
    float* wxb = wxacc + (size_t)b * K_DIM * C_DIM;
#pragma unroll
    for (int rg = 0; rg < 16; ++rg){
        const int row = (rg & 3) + 8 * (rg >> 2) + 4 * hi;   // verified D layout
        atomicAdd(&wxb[row * C_DIM + cmy], acc[rg]);
    }
    if (l31 == 0){
#pragma unroll
        for (int rg = 0; rg < 16; ++rg){
            const int row = (rg & 3) + 8 * (rg >> 2) + 4 * hi;
            atomicAdd(&wsacc[b * K_DIM + row], accS[rg]);
        }
    }
}

// ===================== FALLBACK: proven R5 fused kernel =====================
#define SWZ5(row, n) ((((row) * 64) + (n)) ^ (((row) & 7) << 3))

__global__ __launch_bounds__(64, 2) void enc_main_fused(
    const float* __restrict__ x,
    const unsigned short* __restrict__ cwt2b,
    const float* __restrict__ combo,
    float* __restrict__ wxacc,
    float* __restrict__ wsacc)
{
    __shared__ unsigned short xs[C_DIM * 64];
    __shared__ unsigned short aws[K_DIM * 64];

    const int t   = threadIdx.x;
    const int b   = blockIdx.y;
    const int hi  = t >> 5;
    const int l31 = t & 31;

    const float* xb = x + (size_t)b * C_DIM * N_SP;

    short8 cwA[8];
#pragma unroll
    for (int ksg = 0; ksg < 8; ++ksg)
        cwA[ksg] = *(const short8*)(const void*)(cwt2b + l31 * C_DIM + ksg * 16 + hi * 8);

    f32x16 acc0, acc1, acc2, acc3, accS;
#pragma unroll
    for (int i = 0; i < 16; ++i){
        acc0[i]=0.f; acc1[i]=0.f; acc2[i]=0.f; acc3[i]=0.f; accS[i]=0.f;
    }
    short8 ones;
#pragma unroll
    for (int i = 0; i < 8; ++i) ones[i] = (short)0x3F80;

    for (int tile = 0; tile < 4; ++tile){
        const int n0 = blockIdx.x * 256 + tile * 64;
        const float* xp = xb + n0 + t;
        __syncthreads();

        f32x16 sA, sB;
#pragma unroll
        for (int i = 0; i < 16; ++i){ sA[i]=0.f; sB[i]=0.f; }
        float x2 = 0.f;
        int xr[32];

#pragma unroll
        for (int h = 0; h < 2; ++h){
            const int cb = h * 64;
            float cur[8], nx1[8];
#pragma unroll
            for (int j = 0; j < 8; ++j) cur[j] = xp[(cb + j) * N_SP];
#pragma unroll
            for (int j = 0; j < 8; ++j) nx1[j] = xp[(cb + 8 + j) * N_SP];

#pragma unroll
            for (int g = 0; g < 8; ++g){
                float nx2[8];
                if (g < 6){
#pragma unroll
                    for (int j = 0; j < 8; ++j) nx2[j] = xp[(cb + (g + 2) * 8 + j) * N_SP];
                } else {
#pragma unroll
                    for (int j = 0; j < 8; ++j) nx2[j] = 0.f;
                }
#pragma unroll
                for (int j = 0; j < 8; j += 2){
                    const int cl = g * 8 + j;
                    const int c  = cb + cl;
                    const float a0 = cur[j], a1 = cur[j + 1];
                    x2 = fmaf(a0, a0, x2);
                    x2 = fmaf(a1, a1, x2);
                    const unsigned u0 = f2bfu(a0), u1 = f2bfu(a1);
                    xs[SWZ5(c,     t)] = (unsigned short)u0;
                    xs[SWZ5(c + 1, t)] = (unsigned short)u1;
                    xr[cl >> 1] = (int)(u0 | (u1 << 16));
                }
                if (g < 7){
#pragma unroll
                    for (int j = 0; j < 8; ++j){ cur[j] = nx1[j]; nx1[j] = nx2[j]; }
                }
            }
#pragma unroll
            for (int kl = 0; kl < 4; ++kl){
                FragU f0, f1;
#pragma unroll
                for (int d = 0; d < 4; ++d){
                    const int L  = xr[kl * 8 + d];
                    const int H  = xr[kl * 8 + 4 + d];
                    const int sl = __shfl_xor(L, 32);
                    const int sh = __shfl_xor(H, 32);
                    f0.i[d] = hi ? sh : L;
                    f1.i[d] = hi ? H  : sl;
                }
                sA = __builtin_amdgcn_mfma_f32_32x32x16_bf16(cwA[h*4+kl], f0.s, sA, 0,0,0);
                sB = __builtin_amdgcn_mfma_f32_32x32x16_bf16(cwA[h*4+kl], f1.s, sB, 0,0,0);
            }
        }

        float csx[16], csy[16];
#pragma unroll
        for (int q = 0; q < 16; ++q){
            const int row = (q & 3) + 8 * (q >> 2) + 4 * hi;
            csx[q] = combo[2 * row];
            csy[q] = combo[2 * row + 1];
        }
        const float x2o  = __shfl_xor(x2, 32);
        const float x2g0 = hi ? x2o : x2;
        const float x2g1 = hi ? x2 : x2o;
        {
            float arg[16]; float ml = -3.4e38f;
#pragma unroll
            for (int q = 0; q < 16; ++q){
                arg[q] = fmaf(csx[q], x2g0, sA[q] + csy[q]);
                ml = fmaxf(ml, arg[q]);
            }
            const float mm = fmaxf(ml, __shfl_xor(ml, 32));
            float sum = 0.f;
#pragma unroll
            for (int q = 0; q < 16; ++q){ float p = __expf(arg[q] - mm); arg[q] = p; sum += p; }
            sum += __shfl_xor(sum, 32);
            const float r = 1.f / sum;
#pragma unroll
            for (int q = 0; q < 16; ++q){
                const int row = (q & 3) + 8 * (q >> 2) + 4 * hi;
                aws[SWZ5(row, l31)] = f2bf(arg[q] * r);
            }
        }
        {
            float arg[16]; float ml = -3.4e38f;
#pragma unroll
            for (int q = 0; q < 16; ++q){
                arg[q] = fmaf(csx[q], x2g1, sB[q] + csy[q]);
                ml = fmaxf(ml, arg[q]);
            }
            const float mm = fmaxf(ml, __shfl_xor(ml, 32));
            float sum = 0.f;
#pragma unroll
            for (int q = 0; q < 16; ++q){ float p = __expf(arg[q] - mm); arg[q] = p; sum += p; }
            sum += __shfl_xor(sum, 32);
            const float r = 1.f / sum;
#pragma unroll
            for (int q = 0; q < 16; ++q){
                const int row = (q & 3) + 8 * (q >> 2) + 4 * hi;
                aws[SWZ5(row, 32 + l31)] = f2bf(arg[q] * r);
            }
        }
        __syncthreads();

#pragma unroll
        for (int ks = 0; ks < 4; ++ks){
            const int n8 = ks * 16 + hi * 8;
            short8 af  = *(const short8*)(const void*)&aws[SWZ5(l31, n8)];
            short8 bf0 = *(const short8*)(const void*)&xs[SWZ5(l31,      n8)];
            short8 bf1 = *(const short8*)(const void*)&xs[SWZ5(32 + l31, n8)];
            short8 bf2 = *(const short8*)(const void*)&xs[SWZ5(64 + l31, n8)];
            short8 bf3 = *(const short8*)(const void*)&xs[SWZ5(96 + l31, n8)];
            acc0 = __builtin_amdgcn_mfma_f32_32x32x16_bf16(af, bf0, acc0, 0, 0, 0);
            acc1 = __builtin_amdgcn_mfma_f32_32x32x16_bf16(af, bf1, acc1, 0, 0, 0);
            acc2 = __builtin_amdgcn_mfma_f32_32x32x16_bf16(af, bf2, acc2, 0, 0, 0);
            acc3 = __builtin_amdgcn_mfma_f32_32x32x16_bf16(af, bf3, acc3, 0, 0, 0);
            accS = __builtin_amdgcn_mfma_f32_32x32x16_bf16(af, ones, accS, 0, 0, 0);
        }
    }

    float* wxb = wxacc + (size_t)b * K_DIM * C_DIM;
#pragma unroll
    for (int rg = 0; rg < 16; ++rg){
        const int row = (rg & 3) + 8 * (rg >> 2) + 4 * hi;
        atomicAdd(&wxb[row * C_DIM +      l31], acc0[rg]);
        atomicAdd(&wxb[row * C_DIM + 32 + l31], acc1[rg]);
        atomicAdd(&wxb[row * C_DIM + 64 + l31], acc2[rg]);
        atomicAdd(&wxb[row * C_DIM + 96 + l31], acc3[rg]);
    }
    if (l31 == 0){
#pragma unroll
        for (int rg = 0; rg < 16; ++rg){
            const int row = (rg & 3) + 8 * (rg >> 2) + 4 * hi;
            atomicAdd(&wsacc[b * K_DIM + row], accS[rg]);
        }
    }
}

// ============================== small kernels ===============================
__global__ void enc_zero(float* __restrict__ p, int n){
    const int i = blockIdx.x * 256 + threadIdx.x;
    if (i < n) p[i] = 0.f;
}

__global__ void enc_prep(const float* __restrict__ cw, const float* __restrict__ scale,
                         unsigned short* __restrict__ cwt2b, float* __restrict__ combo){
    const int t = threadIdx.x;  // 128 threads; t = c
    for (int k = 0; k < K_DIM; ++k)
        cwt2b[k * C_DIM + t] = f2bf(-2.f * scale[k] * cw[k * C_DIM + t]);
    if (t < K_DIM){
        float s = 0.f;
        for (int c = 0; c < C_DIM; ++c){
            float v = cw[t * C_DIM + c];
            s = fmaf(v, v, s);
        }
        combo[2 * t]     = scale[t];
        combo[2 * t + 1] = scale[t] * s;
    }
}

__global__ void enc_final(const float* __restrict__ wxacc, const float* __restrict__ wsacc,
                          const float* __restrict__ cw, float* __restrict__ out){
    const int i  = blockIdx.x * 256 + threadIdx.x;  // B*K*C = 131072
    const int c  = i & (C_DIM - 1);
    const int kk = (i >> 7) & (K_DIM - 1);
    const int bk = i >> 7;
    out[i] = wxacc[i] - wsacc[bk] * cw[kk * C_DIM + c];
}

extern "C" void kernel_launch(void* const* d_in, const int* in_sizes, int n_in,
                              void* d_out, int out_size, void* d_ws, size_t ws_size,
                              hipStream_t stream){
    (void)in_sizes; (void)n_in; (void)out_size;
    const float* x     = (const float*)d_in[0];
    const float* cw    = (const float*)d_in[1];
    const float* scale = (const float*)d_in[2];
    float* out = (float*)d_out;

    // workspace carve (bytes)
    char* p = (char*)d_ws;
    float* wxacc = (float*)p;            p += (size_t)B_DIM * K_DIM * C_DIM * 4;  // 512 KB
    float* wsacc = (float*)p;            p += (size_t)B_DIM * K_DIM * 4;
    float* combo = (float*)p;            p += 64 * 4;
    unsigned short* cwt2b = (unsigned short*)p; p += K_DIM * C_DIM * 2;
    unsigned short* xt    = (unsigned short*)p; p += (size_t)B_DIM * N_SP * C_DIM * 2; // 128 MB
    float* x2p   = (float*)p;            p += (size_t)4 * B_DIM * N_SP * 4;            // 8 MB
    const size_t needed = (size_t)(p - (char*)d_ws);

    const int nz = B_DIM * K_DIM * C_DIM + B_DIM * K_DIM;
    enc_zero<<<(nz + 255) / 256, 256, 0, stream>>>(wxacc, nz);
    enc_prep<<<1, 128, 0, stream>>>(cw, scale, cwt2b, combo);

    if (ws_size >= needed){
        enc_transpose<<<dim3(16, B_DIM, 4), 256, 0, stream>>>(x, xt, x2p);
        enc_main2<<<dim3(128, B_DIM), 256, 0, stream>>>(xt, x2p, cwt2b, combo, wxacc, wsacc);
    } else {
        enc_main_fused<<<dim3(64, B_DIM), 64, 0, stream>>>(x, cwt2b, combo, wxacc, wsacc);
    }
    enc_final<<<512, 256, 0, stream>>>(wxacc, wsacc, cw, out);
}

// Round 10
// 117.589 us; speedup vs baseline: 3.7653x; 3.7653x over previous
//
#include <hip/hip_runtime.h>

#define N_SP 16384
#define C_DIM 128
#define K_DIM 32
#define NBX   64     // blocks along n
#define TILEN 64     // n per tile
#define TILES 4      // tiles per block; NBX*TILES*TILEN == N_SP

typedef short short8 __attribute__((ext_vector_type(8)));
typedef float f32x16 __attribute__((ext_vector_type(16)));

__device__ __forceinline__ unsigned f2bfu(float f){
    return (__float_as_uint(f) + 0x8000u) >> 16;   // cheap RN to bf16 bits
}
__device__ __forceinline__ unsigned short f2bf(float f){
    return (unsigned short)f2bfu(f);
}

// swizzled index into a [row][64] ushort LDS tile: XOR bits 3..5 of n with row&7
#define SWZ(row, n) ((((row) * 64) + (n)) ^ (((row) & 7) << 3))

union FragU { int i[4]; short8 s; };

__global__ __launch_bounds__(64, 2) void enc_main(
    const float* __restrict__ x,              // [B][C][N]
    const unsigned short* __restrict__ cwt2b, // [K][C] bf16 of -2*scale[k]*cw[k][c]
    const float* __restrict__ combo,          // [K][2] = {scale[k], scale[k]*||cw_k||^2}
    float* __restrict__ wxp,                  // [2048][K][C] block partials
    float* __restrict__ wsp)                  // [2048][K]    block partials
{
    __shared__ unsigned short xs[C_DIM * TILEN];   // bf16 x[c][n'] swizzled (16 KB)
    __shared__ unsigned short aws[K_DIM * TILEN];  // bf16 aw[k][n'] swizzled (4 KB)

    const int t   = threadIdx.x;   // 0..63, one wave; thread t owns n-column n0+t
    const int b   = blockIdx.y;
    const int hi  = t >> 5;
    const int l31 = t & 31;

    const float* xb = x + (size_t)b * C_DIM * N_SP;

    // held codeword A-fragments: lane l31 = k-row, hi picks 8-c half of each 16-chunk
    short8 cwA[8];
#pragma unroll
    for (int ksg = 0; ksg < 8; ++ksg)
        cwA[ksg] = *(const short8*)(const void*)(cwt2b + l31 * C_DIM + ksg * 16 + hi * 8);

    f32x16 acc0, acc1, acc2, acc3, accS;
#pragma unroll
    for (int i = 0; i < 16; ++i){
        acc0[i]=0.f; acc1[i]=0.f; acc2[i]=0.f; acc3[i]=0.f; accS[i]=0.f;
    }
    short8 ones;
#pragma unroll
    for (int i = 0; i < 8; ++i) ones[i] = (short)0x3F80;  // bf16 1.0

    for (int tile = 0; tile < TILES; ++tile){
        const int n0 = blockIdx.x * (TILES * TILEN) + tile * TILEN;
        const float* xp = xb + n0 + t;

        __syncthreads();   // xs/aws safe to overwrite (prev tile's phase-D done)

        f32x16 sA, sB;     // S[k][n] accumulators: group0 cols n=l31, group1 n=32+l31
#pragma unroll
        for (int i = 0; i < 16; ++i){ sA[i]=0.f; sB[i]=0.f; }

        float x2 = 0.f;
        int xr[32];        // packed bf16 of this thread's n-column, current c-half

#pragma unroll
        for (int h = 0; h < 2; ++h){
            const int cb = h * 64;
            // ---- stream 64 c-rows (depth-2, 8-wide), fp32 x2, stage xs, pack xr ----
            float cur[8], nx1[8];
#pragma unroll
            for (int j = 0; j < 8; ++j) cur[j] = xp[(cb + j) * N_SP];
#pragma unroll
            for (int j = 0; j < 8; ++j) nx1[j] = xp[(cb + 8 + j) * N_SP];

#pragma unroll
            for (int g = 0; g < 8; ++g){
                float nx2[8];
                if (g < 6){
#pragma unroll
                    for (int j = 0; j < 8; ++j) nx2[j] = xp[(cb + (g + 2) * 8 + j) * N_SP];
                } else {
#pragma unroll
                    for (int j = 0; j < 8; ++j) nx2[j] = 0.f;
                }
#pragma unroll
                for (int j = 0; j < 8; j += 2){
                    const int cl = g * 8 + j;      // local c in half (0..63)
                    const int c  = cb + cl;
                    const float a0 = cur[j], a1 = cur[j + 1];
                    x2 = fmaf(a0, a0, x2);
                    x2 = fmaf(a1, a1, x2);
                    const unsigned u0 = f2bfu(a0), u1 = f2bfu(a1);
                    xs[SWZ(c,     t)] = (unsigned short)u0;
                    xs[SWZ(c + 1, t)] = (unsigned short)u1;
                    xr[cl >> 1] = (int)(u0 | (u1 << 16));
                }
                if (g < 7){
#pragma unroll
                    for (int j = 0; j < 8; ++j){ cur[j] = nx1[j]; nx1[j] = nx2[j]; }
                }
            }

            // S += cwt2 * x via MFMA; B-frags built from registers via lane-swap
#pragma unroll
            for (int kl = 0; kl < 4; ++kl){
                FragU f0, f1;
#pragma unroll
                for (int d = 0; d < 4; ++d){
                    const int L  = xr[kl * 8 + d];        // c = kl*16 + 2d,2d+1
                    const int H  = xr[kl * 8 + 4 + d];    // c = kl*16+8 + 2d,2d+1
                    const int sl = __shfl_xor(L, 32);
                    const int sh = __shfl_xor(H, 32);
                    f0.i[d] = hi ? sh : L;   // col n=l31     : owner thread l31
                    f1.i[d] = hi ? H  : sl;  // col n=32+l31  : owner thread 32+l31
                }
                sA = __builtin_amdgcn_mfma_f32_32x32x16_bf16(cwA[h*4+kl], f0.s, sA, 0,0,0);
                sB = __builtin_amdgcn_mfma_f32_32x32x16_bf16(cwA[h*4+kl], f1.s, sB, 0,0,0);
            }
        }

        // ---- softmax over k on the MFMA D-layout ----
        float csx[16], csy[16];
#pragma unroll
        for (int q = 0; q < 16; ++q){
            const int row = (q & 3) + 8 * (q >> 2) + 4 * hi;
            csx[q] = combo[2 * row];
            csy[q] = combo[2 * row + 1];
        }
        const float x2o  = __shfl_xor(x2, 32);
        const float x2g0 = hi ? x2o : x2;   // x2[n=l31]
        const float x2g1 = hi ? x2 : x2o;   // x2[n=32+l31]

        {   // group 0: cols n = l31
            float arg[16]; float ml = -3.4e38f;
#pragma unroll
            for (int q = 0; q < 16; ++q){
                arg[q] = fmaf(csx[q], x2g0, sA[q] + csy[q]);
                ml = fmaxf(ml, arg[q]);
            }
            const float mm = fmaxf(ml, __shfl_xor(ml, 32));
            float sum = 0.f;
#pragma unroll
            for (int q = 0; q < 16; ++q){ float p = __expf(arg[q] - mm); arg[q] = p; sum += p; }
            sum += __shfl_xor(sum, 32);
            const float r = 1.f / sum;
#pragma unroll
            for (int q = 0; q < 16; ++q){
                const int row = (q & 3) + 8 * (q >> 2) + 4 * hi;
                aws[SWZ(row, l31)] = f2bf(arg[q] * r);
            }
        }
        {   // group 1: cols n = 32 + l31
            float arg[16]; float ml = -3.4e38f;
#pragma unroll
            for (int q = 0; q < 16; ++q){
                arg[q] = fmaf(csx[q], x2g1, sB[q] + csy[q]);
                ml = fmaxf(ml, arg[q]);
            }
            const float mm = fmaxf(ml, __shfl_xor(ml, 32));
            float sum = 0.f;
#pragma unroll
            for (int q = 0; q < 16; ++q){ float p = __expf(arg[q] - mm); arg[q] = p; sum += p; }
            sum += __shfl_xor(sum, 32);
            const float r = 1.f / sum;
#pragma unroll
            for (int q = 0; q < 16; ++q){
                const int row = (q & 3) + 8 * (q >> 2) + 4 * hi;
                aws[SWZ(row, 32 + l31)] = f2bf(arg[q] * r);
            }
        }

        __syncthreads();

        // ---- phase D: wx[k][c] += aw[k][n] * x[n][c] via MFMA (acc across tiles) ----
#pragma unroll
        for (int ks = 0; ks < 4; ++ks){            // Kdim = n = 64 -> 4 steps of 16
            const int n8 = ks * 16 + hi * 8;
            short8 af  = *(const short8*)(const void*)&aws[SWZ(l31, n8)];
            short8 bf0 = *(const short8*)(const void*)&xs[SWZ(l31,      n8)];
            short8 bf1 = *(const short8*)(const void*)&xs[SWZ(32 + l31, n8)];
            short8 bf2 = *(const short8*)(const void*)&xs[SWZ(64 + l31, n8)];
            short8 bf3 = *(const short8*)(const void*)&xs[SWZ(96 + l31, n8)];
            acc0 = __builtin_amdgcn_mfma_f32_32x32x16_bf16(af, bf0, acc0, 0, 0, 0);
            acc1 = __builtin_amdgcn_mfma_f32_32x32x16_bf16(af, bf1, acc1, 0, 0, 0);
            acc2 = __builtin_amdgcn_mfma_f32_32x32x16_bf16(af, bf2, acc2, 0, 0, 0);
            acc3 = __builtin_amdgcn_mfma_f32_32x32x16_bf16(af, bf3, acc3, 0, 0, 0);
            accS = __builtin_amdgcn_mfma_f32_32x32x16_bf16(af, ones, accS, 0, 0, 0);
        }
    }

    // ---- epilogue: block-private partial stores (NO atomics) ----
    const int blk = b * NBX + blockIdx.x;
    float* wxp_blk = wxp + (size_t)blk * (K_DIM * C_DIM);
#pragma unroll
    for (int rg = 0; rg < 16; ++rg){
        const int row = (rg & 3) + 8 * (rg >> 2) + 4 * hi;  // verified D layout
        wxp_blk[row * C_DIM +      l31] = acc0[rg];
        wxp_blk[row * C_DIM + 32 + l31] = acc1[rg];
        wxp_blk[row * C_DIM + 64 + l31] = acc2[rg];
        wxp_blk[row * C_DIM + 96 + l31] = acc3[rg];
    }
    if (l31 == 0){
        float* wsp_blk = wsp + (size_t)blk * K_DIM;
#pragma unroll
        for (int rg = 0; rg < 16; ++rg){
            const int row = (rg & 3) + 8 * (rg >> 2) + 4 * hi;
            wsp_blk[row] = accS[rg];
        }
    }
}

__global__ void enc_prep(const float* __restrict__ cw, const float* __restrict__ scale,
                         unsigned short* __restrict__ cwt2b, float* __restrict__ combo){
    const int t = threadIdx.x;  // 128 threads; t = c
    for (int k = 0; k < K_DIM; ++k)
        cwt2b[k * C_DIM + t] = f2bf(-2.f * scale[k] * cw[k * C_DIM + t]);
    if (t < K_DIM){
        float s = 0.f;
        for (int c = 0; c < C_DIM; ++c){
            float v = cw[t * C_DIM + c];
            s = fmaf(v, v, s);
        }
        combo[2 * t]     = scale[t];
        combo[2 * t + 1] = scale[t] * s;
    }
}

// out[b][k][c] = sum_j wxp[b*64+j][k][c] - (sum_j wsp[b*64+j][k]) * cw[k][c]
__global__ __launch_bounds__(128) void enc_reduce(
    const float* __restrict__ wxp, const float* __restrict__ wsp,
    const float* __restrict__ cw, float* __restrict__ out)
{
    const int c = threadIdx.x;          // 0..127
    const int k = blockIdx.x & (K_DIM - 1);
    const int b = blockIdx.x >> 5;      // grid = 32*32 = 1024 blocks

    __shared__ float wsh;
    if (c < 64){
        float wv = wsp[(size_t)(b * NBX + c) * K_DIM + k];
#pragma unroll
        for (int off = 32; off; off >>= 1) wv += __shfl_down(wv, off);
        if (c == 0) wsh = wv;
    }
    __syncthreads();

    float s0 = 0.f, s1 = 0.f, s2 = 0.f, s3 = 0.f;
    const float* p = wxp + (size_t)(b * NBX) * (K_DIM * C_DIM) + k * C_DIM + c;
#pragma unroll
    for (int j = 0; j < NBX; j += 4){
        s0 += p[(size_t)(j + 0) * (K_DIM * C_DIM)];
        s1 += p[(size_t)(j + 1) * (K_DIM * C_DIM)];
        s2 += p[(size_t)(j + 2) * (K_DIM * C_DIM)];
        s3 += p[(size_t)(j + 3) * (K_DIM * C_DIM)];
    }
    out[((size_t)b * K_DIM + k) * C_DIM + c] = (s0 + s1) + (s2 + s3) - wsh * cw[k * C_DIM + c];
}

extern "C" void kernel_launch(void* const* d_in, const int* in_sizes, int n_in,
                              void* d_out, int out_size, void* d_ws, size_t ws_size,
                              hipStream_t stream){
    (void)in_sizes; (void)n_in; (void)out_size; (void)ws_size;
    const float* x     = (const float*)d_in[0];
    const float* cw    = (const float*)d_in[1];
    const float* scale = (const float*)d_in[2];
    float* out = (float*)d_out;

    // workspace carve
    char* p = (char*)d_ws;
    float* combo = (float*)p;                    p += 64 * sizeof(float);
    unsigned short* cwt2b = (unsigned short*)p;  p += K_DIM * C_DIM * sizeof(unsigned short);
    float* wxp = (float*)p;                      p += (size_t)2048 * K_DIM * C_DIM * sizeof(float); // 33.5 MB
    float* wsp = (float*)p;                      // 2048*32*4 = 256 KB

    enc_prep<<<1, 128, 0, stream>>>(cw, scale, cwt2b, combo);
    enc_main<<<dim3(NBX, 32), 64, 0, stream>>>(x, cwt2b, combo, wxp, wsp);
    enc_reduce<<<32 * K_DIM, 128, 0, stream>>>(wxp, wsp, cw, out);
}

// Round 11
// 87.657 us; speedup vs baseline: 5.0510x; 1.3415x over previous
//
#include <hip/hip_runtime.h>

#define N_SP 16384
#define C_DIM 128
#define K_DIM 32
#define TILEN 32
#define NBP   96     // partial blocks per batch: 32 do 6 tiles, 64 do 5 (32*192+64*160=16384)
#define XPAD  40     // padded row length (ushorts): 80B stride, 16B-aligned, banks spread

typedef short short8 __attribute__((ext_vector_type(8)));
typedef float f32x16 __attribute__((ext_vector_type(16)));

__device__ __forceinline__ unsigned f2bfu(float f){
    return (__float_as_uint(f) + 0x8000u) >> 16;   // cheap RN to bf16 bits
}
__device__ __forceinline__ unsigned short f2bf(float f){
    return (unsigned short)f2bfu(f);
}

union FragU { int i[4]; short8 s; };

__global__ __launch_bounds__(64) void enc_main(
    const float* __restrict__ x,              // [B][C][N]
    const unsigned short* __restrict__ cwt2b, // [K][C] bf16 of -2*scale[k]*cw[k][c]
    const float* __restrict__ combo,          // [K][2] = {scale[k], scale[k]*||cw_k||^2}
    float* __restrict__ wxp,                  // [32*NBP][K][C] block partials
    float* __restrict__ wsp)                  // [32*NBP][K]    block partials
{
    __shared__ unsigned short xs[C_DIM * XPAD];   // bf16 x[c][n'], padded (10 KB)
    __shared__ unsigned short aws[K_DIM * XPAD];  // bf16 aw[k][n'], padded (2.5 KB)

    const int t   = threadIdx.x;   // one wave; thread owns (col l31, c-half hi*64..+63)
    const int r   = blockIdx.x;    // 0..NBP-1
    const int b   = blockIdx.y;
    const int hi  = t >> 5;
    const int l31 = t & 31;

    const int nt    = (r < 32) ? 6 : 5;
    const int nbase = (r < 32) ? r * 192 : 6144 + (r - 32) * 160;

    const float* xb = x + (size_t)b * C_DIM * N_SP + (size_t)(hi * 64) * N_SP;

    // held codeword A-fragments: lane l31 = k-row, hi picks 8-c half of each 16-chunk
    short8 cwA[8];
#pragma unroll
    for (int ksg = 0; ksg < 8; ++ksg)
        cwA[ksg] = *(const short8*)(const void*)(cwt2b + l31 * C_DIM + ksg * 16 + hi * 8);

    // hoisted softmax constants (tile-invariant)
    float csx[16], csy[16];
#pragma unroll
    for (int q = 0; q < 16; ++q){
        const int row = (q & 3) + 8 * (q >> 2) + 4 * hi;
        csx[q] = combo[2 * row];
        csy[q] = combo[2 * row + 1];
    }

    f32x16 acc0, acc1, acc2, acc3, accS;
#pragma unroll
    for (int i = 0; i < 16; ++i){
        acc0[i]=0.f; acc1[i]=0.f; acc2[i]=0.f; acc3[i]=0.f; accS[i]=0.f;
    }
    short8 ones;
#pragma unroll
    for (int i = 0; i < 8; ++i) ones[i] = (short)0x3F80;  // bf16 1.0

#pragma unroll 1
    for (int tile = 0; tile < nt; ++tile){
        const int n0 = nbase + tile * TILEN;
        const float* xp = xb + n0 + l31;

        __syncthreads();   // xs/aws safe to overwrite (prev tile's phase-D done)

        f32x16 sA;         // S[k][n] accumulator, cols n = l31
#pragma unroll
        for (int i = 0; i < 16; ++i) sA[i] = 0.f;

        float x2 = 0.f;    // partial ||x||^2 over this thread's 64 c-rows
        int xr[32];        // packed bf16 pairs: xr[m] = rows 2m,2m+1 (local)

        // ---- phase 1: stream 64 c-rows (depth-2, 8-wide), stage bf16 ----
        float cur[8], nx1[8];
#pragma unroll
        for (int j = 0; j < 8; ++j) cur[j] = xp[(size_t)j * N_SP];
#pragma unroll
        for (int j = 0; j < 8; ++j) nx1[j] = xp[(size_t)(8 + j) * N_SP];

#pragma unroll
        for (int g = 0; g < 8; ++g){
            float nx2[8];
            if (g < 6){
#pragma unroll
                for (int j = 0; j < 8; ++j) nx2[j] = xp[(size_t)((g + 2) * 8 + j) * N_SP];
            } else {
#pragma unroll
                for (int j = 0; j < 8; ++j) nx2[j] = 0.f;
            }
#pragma unroll
            for (int j = 0; j < 8; j += 2){
                const int rl = g * 8 + j;        // local row 0..63
                const int c  = hi * 64 + rl;     // global c-row
                const float a0 = cur[j], a1 = cur[j + 1];
                x2 = fmaf(a0, a0, x2);
                x2 = fmaf(a1, a1, x2);
                const unsigned u0 = f2bfu(a0), u1 = f2bfu(a1);
                xs[c * XPAD + l31]       = (unsigned short)u0;
                xs[(c + 1) * XPAD + l31] = (unsigned short)u1;
                xr[rl >> 1] = (int)(u0 | (u1 << 16));
            }
            if (g < 7){
#pragma unroll
                for (int j = 0; j < 8; ++j){ cur[j] = nx1[j]; nx1[j] = nx2[j]; }
            }
        }

        // ---- phase S: S[k][col l31] += cwt2[k][c] * x[c][col], 8 c-steps of 16 ----
        // pair (t, t^32) holds same column, different c-half; exchange via shfl_xor
#pragma unroll
        for (int ks = 0; ks < 8; ++ks){
            FragU f;
            if (ks < 4){
                // owner of c = ks*16.. is the hi=0 thread
#pragma unroll
                for (int d = 0; d < 4; ++d){
                    const int own = xr[ks * 8 + d];                    // c = ks*16+2d    (hi=0 slice)
                    const int oth = __shfl_xor(xr[ks * 8 + 4 + d], 32);// c = ks*16+8+2d  from partner
                    f.i[d] = hi ? oth : own;
                }
            } else {
                // owner of c = ks*16.. is the hi=1 thread (local rl = c-64)
                const int k4 = ks - 4;
#pragma unroll
                for (int d = 0; d < 4; ++d){
                    const int own = xr[k4 * 8 + 4 + d];                // c = ks*16+8+2d (hi=1 slice)
                    const int oth = __shfl_xor(xr[k4 * 8 + d], 32);    // c = ks*16+2d   from partner
                    f.i[d] = hi ? own : oth;
                }
            }
            sA = __builtin_amdgcn_mfma_f32_32x32x16_bf16(cwA[ks], f.s, sA, 0, 0, 0);
        }

        // ---- phase 2: softmax over k (col l31), D-layout ----
        const float x2f = x2 + __shfl_xor(x2, 32);   // full ||x||^2 for col l31
        {
            float arg[16]; float ml = -3.4e38f;
#pragma unroll
            for (int q = 0; q < 16; ++q){
                arg[q] = fmaf(csx[q], x2f, sA[q] + csy[q]);  // scale*(x2-2x.cw+c2)
                ml = fmaxf(ml, arg[q]);
            }
            const float mm = fmaxf(ml, __shfl_xor(ml, 32));
            float sum = 0.f;
#pragma unroll
            for (int q = 0; q < 16; ++q){ float p = __expf(arg[q] - mm); arg[q] = p; sum += p; }
            sum += __shfl_xor(sum, 32);
            const float rr = 1.f / sum;
#pragma unroll
            for (int q = 0; q < 16; ++q){
                const int row = (q & 3) + 8 * (q >> 2) + 4 * hi;
                aws[row * XPAD + l31] = f2bf(arg[q] * rr);
            }
        }

        __syncthreads();   // aws complete

        // ---- phase D: wx[k][c] += aw[k][n] * x[n][c], 2 n-steps of 16 ----
#pragma unroll
        for (int ks = 0; ks < 2; ++ks){
            const int n8 = ks * 16 + hi * 8;
            short8 af  = *(const short8*)(const void*)&aws[l31 * XPAD + n8];
            short8 bf0 = *(const short8*)(const void*)&xs[(l31)       * XPAD + n8];
            short8 bf1 = *(const short8*)(const void*)&xs[(32 + l31)  * XPAD + n8];
            short8 bf2 = *(const short8*)(const void*)&xs[(64 + l31)  * XPAD + n8];
            short8 bf3 = *(const short8*)(const void*)&xs[(96 + l31)  * XPAD + n8];
            acc0 = __builtin_amdgcn_mfma_f32_32x32x16_bf16(af, bf0, acc0, 0, 0, 0);
            acc1 = __builtin_amdgcn_mfma_f32_32x32x16_bf16(af, bf1, acc1, 0, 0, 0);
            acc2 = __builtin_amdgcn_mfma_f32_32x32x16_bf16(af, bf2, acc2, 0, 0, 0);
            acc3 = __builtin_amdgcn_mfma_f32_32x32x16_bf16(af, bf3, acc3, 0, 0, 0);
            accS = __builtin_amdgcn_mfma_f32_32x32x16_bf16(af, ones, accS, 0, 0, 0);
        }
    }

    // ---- epilogue: block-private partial stores (no atomics) ----
    const int blk = b * NBP + r;
    float* wxp_blk = wxp + (size_t)blk * (K_DIM * C_DIM);
#pragma unroll
    for (int rg = 0; rg < 16; ++rg){
        const int row = (rg & 3) + 8 * (rg >> 2) + 4 * hi;  // verified D layout
        wxp_blk[row * C_DIM +      l31] = acc0[rg];
        wxp_blk[row * C_DIM + 32 + l31] = acc1[rg];
        wxp_blk[row * C_DIM + 64 + l31] = acc2[rg];
        wxp_blk[row * C_DIM + 96 + l31] = acc3[rg];
    }
    if (l31 == 0){
        float* wsp_blk = wsp + (size_t)blk * K_DIM;
#pragma unroll
        for (int rg = 0; rg < 16; ++rg){
            const int row = (rg & 3) + 8 * (rg >> 2) + 4 * hi;
            wsp_blk[row] = accS[rg];
        }
    }
}

__global__ void enc_prep(const float* __restrict__ cw, const float* __restrict__ scale,
                         unsigned short* __restrict__ cwt2b, float* __restrict__ combo){
    const int t = threadIdx.x;  // 128 threads; t = c
    for (int k = 0; k < K_DIM; ++k)
        cwt2b[k * C_DIM + t] = f2bf(-2.f * scale[k] * cw[k * C_DIM + t]);
    if (t < K_DIM){
        float s = 0.f;
        for (int c = 0; c < C_DIM; ++c){
            float v = cw[t * C_DIM + c];
            s = fmaf(v, v, s);
        }
        combo[2 * t]     = scale[t];
        combo[2 * t + 1] = scale[t] * s;
    }
}

// out[b][k][c] = sum_j wxp[b*NBP+j][k][c] - (sum_j wsp[b*NBP+j][k]) * cw[k][c]
__global__ __launch_bounds__(256) void enc_reduce(
    const float* __restrict__ wxp, const float* __restrict__ wsp,
    const float* __restrict__ cw, float* __restrict__ out)
{
    const int t = threadIdx.x;          // 0..255
    const int k = blockIdx.x & (K_DIM - 1);
    const int b = blockIdx.x >> 5;      // grid = 32*32

    __shared__ float ps[8][C_DIM];
    __shared__ float wsl[4];

    // wsum: threads 0..95 load one partial each, wave-reduce
    float wv = (t < NBP) ? wsp[(size_t)(b * NBP + t) * K_DIM + k] : 0.f;
#pragma unroll
    for (int off = 32; off; off >>= 1) wv += __shfl_down(wv, off);
    if ((t & 63) == 0) wsl[t >> 6] = wv;

    // wx: thread (jg = t>>5, c4 = (t&31)*4) sums 12 partials as float4
    const int c4 = (t & 31) * 4;
    const int jg = t >> 5;              // 0..7
    float4 s; s.x = 0.f; s.y = 0.f; s.z = 0.f; s.w = 0.f;
    const float* pp = wxp + ((size_t)(b * NBP) + jg) * (K_DIM * C_DIM) + k * C_DIM + c4;
#pragma unroll
    for (int j = 0; j < NBP; j += 8){   // 12 iterations
        float4 v = *(const float4*)(pp + (size_t)j * (K_DIM * C_DIM));
        s.x += v.x; s.y += v.y; s.z += v.z; s.w += v.w;
    }
    *(float4*)&ps[jg][c4] = s;
    __syncthreads();

    if (t < C_DIM){
        const float wsh = wsl[0] + wsl[1];
        float rsum = 0.f;
#pragma unroll
        for (int j2 = 0; j2 < 8; ++j2) rsum += ps[j2][t];
        out[((size_t)b * K_DIM + k) * C_DIM + t] = rsum - wsh * cw[k * C_DIM + t];
    }
}

extern "C" void kernel_launch(void* const* d_in, const int* in_sizes, int n_in,
                              void* d_out, int out_size, void* d_ws, size_t ws_size,
                              hipStream_t stream){
    (void)in_sizes; (void)n_in; (void)out_size; (void)ws_size;
    const float* x     = (const float*)d_in[0];
    const float* cw    = (const float*)d_in[1];
    const float* scale = (const float*)d_in[2];
    float* out = (float*)d_out;

    // workspace carve
    char* p = (char*)d_ws;
    float* combo = (float*)p;                    p += 64 * sizeof(float);
    unsigned short* cwt2b = (unsigned short*)p;  p += K_DIM * C_DIM * sizeof(unsigned short);
    float* wxp = (float*)p;                      p += (size_t)32 * NBP * K_DIM * C_DIM * sizeof(float); // 50.3 MB
    float* wsp = (float*)p;                      // 32*NBP*K*4 = 393 KB

    enc_prep<<<1, 128, 0, stream>>>(cw, scale, cwt2b, combo);
    enc_main<<<dim3(NBP, 32), 64, 0, stream>>>(x, cwt2b, combo, wxp, wsp);
    enc_reduce<<<32 * K_DIM, 256, 0, stream>>>(wxp, wsp, cw, out);
}